// Round 14
// baseline (95.258 us; speedup 1.0000x reference)
//
#include <hip/hip_runtime.h>
#include <cstdint>
#include <cstring>
#include <cmath>

// ========== Threefry2x32 (JAX, 20 rounds) — core verified on-device via KAT (R3) ==========
__host__ __device__ static inline uint32_t rotl32(uint32_t x, int r) {
  return (x << r) | (x >> (32 - r));
}

__host__ __device__ static inline void tf2x32(uint32_t k0, uint32_t k1,
                                              uint32_t c0, uint32_t c1,
                                              uint32_t& o0, uint32_t& o1) {
  const uint32_t ks2 = 0x1BD11BDAu ^ k0 ^ k1;
  uint32_t x0 = c0 + k0;
  uint32_t x1 = c1 + k1;
#define TF_QR(r) { x0 += x1; x1 = rotl32(x1, (r)); x1 ^= x0; }
  TF_QR(13) TF_QR(15) TF_QR(26) TF_QR(6)
  x0 += k1;  x1 += ks2 + 1u;
  TF_QR(17) TF_QR(29) TF_QR(16) TF_QR(24)
  x0 += ks2; x1 += k0 + 2u;
  TF_QR(13) TF_QR(15) TF_QR(26) TF_QR(6)
  x0 += k0;  x1 += k1 + 3u;
  TF_QR(17) TF_QR(29) TF_QR(16) TF_QR(24)
  x0 += k1;  x1 += ks2 + 4u;
  TF_QR(13) TF_QR(15) TF_QR(26) TF_QR(6)
  x0 += ks2; x1 += k0 + 5u;
#undef TF_QR
  o0 = x0; o1 = x1;
}

// partitionable 32-bit draw at flat index i: counter (0, i), bits = o0 ^ o1
__host__ __device__ static inline uint32_t tf_bits32(uint32_t k0, uint32_t k1, uint32_t i) {
  uint32_t a, b;
  tf2x32(k0, k1, 0u, i, a, b);
  return a ^ b;
}

__device__ static inline float noise_from_bits(uint32_t bits) {
  uint32_t fb = (bits >> 9) | 0x3f800000u;
  float f = __uint_as_float(fb) - 1.0f;
  float v = f * 2.0f - 1.0f;
  v = fmaxf(-1.0f, v);
  return 0.15f * v;
}

// bilinear resize tap, BIT-IDENTICAL expressions to the verified k_resize (R13-verified)
__device__ static inline void resize_rgb(const float* __restrict__ adv, int inS, int S,
                                         int x, int y, float bmul, float rgb[3]) {
  float fs = (float)inS / (float)S;
  float fy = ((float)y + 0.5f) * fs - 0.5f;
  float fx = ((float)x + 0.5f) * fs - 0.5f;
  float y0f = floorf(fy), x0f = floorf(fx);
  float ty = fy - y0f, tx = fx - x0f;
  int y0 = (int)y0f, x0 = (int)x0f;
  int y1 = y0 + 1, x1 = x0 + 1;
  y0 = min(max(y0, 0), inS - 1); y1 = min(max(y1, 0), inS - 1);
  x0 = min(max(x0, 0), inS - 1); x1 = min(max(x1, 0), inS - 1);
  float w00 = (1.f - ty) * (1.f - tx), w01 = (1.f - ty) * tx;
  float w10 = ty * (1.f - tx),         w11 = ty * tx;
#pragma unroll
  for (int c = 0; c < 3; ++c) {
    const float* pc = adv + (size_t)c * inS * inS;
    float v = pc[y0 * inS + x0] * w00 + pc[y0 * inS + x1] * w01 +
              pc[y1 * inS + x0] * w10 + pc[y1 * inS + x1] * w11;
    rgb[c] = v * bmul;
  }
}

// ========== Shared zero role (verified R10-R13): group g -> exterior test, 6x float4 zeros ==
__device__ static inline void zero_role(int g, int Gtot, int N, int S, int X8,
                                        int blo, int bhi, float4* __restrict__ out,
                                        float h0, float h1, float h2, float h3,
                                        float h4, float h5, float h6, float h7) {
  if (g >= Gtot) return;
  int x8 = g % X8;
  int t2 = g / X8;
  int y  = t2 % S;
  int n  = t2 / S;
  float yo  = (float)y + 0.5f;
  float xo0 = (float)(x8 * 8) + 0.5f;
  float xo7 = xo0 + 7.0f;
  float den0 = h6 * xo0 + h7 * yo + 1.0f;
  float den7 = h6 * xo7 + h7 * yo + 1.0f;
  float psx0 = (h0 * xo0 + h1 * yo + h2) / den0 - 0.5f;
  float psy0 = (h3 * xo0 + h4 * yo + h5) / den0 - 0.5f;
  float psx7 = (h0 * xo7 + h1 * yo + h2) / den7 - 0.5f;
  float psy7 = (h3 * xo7 + h4 * yo + h5) / den7 - 0.5f;
  float lox = fminf(psx0, psx7), hix = fmaxf(psx0, psx7);
  float loy = fminf(psy0, psy7), hiy = fmaxf(psy0, psy7);
  float bl = (float)blo - 1.5f, bh = (float)bhi + 1.5f;
  bool exterior = (den0 > 0.0f) && (den7 > 0.0f) &&
                  (hix < bl || lox > bh || hiy < bl || loy > bh);
  if (!exterior) return;                   // interior role (K2) writes this group
  int X4 = X8 * 2;
  size_t obase = ((size_t)(n * 3) * S + y) * X4 + x8 * 2;
  size_t ostride = (size_t)S * X4;
  float4 z = make_float4(0.f, 0.f, 0.f, 0.f);
  out[obase]                = z;
  out[obase + 1]            = z;
  out[obase + ostride]      = z;
  out[obase + ostride + 1]  = z;
  out[obase + 2 * ostride]     = z;
  out[obase + 2 * ostride + 1] = z;
}

#define NCHUNK 8   // n-values per hash thread (amortizes the resize recompute 8x)

// ================= Kernel 1: [resize-partials | n-amortized hash->b1(+W) | zero-exterior] ==
// All three roles mutually independent (deferred-mean makes hash m-free; hash recomputes
// resize taps ONCE per (pixel, n-chunk), bit-identical expressions, R13-verified).
__global__ void __launch_bounds__(256)
k_fused(const float* __restrict__ adv, float4* __restrict__ b1,
        double* __restrict__ part, int nbRes,
        float bmul, float cc, float ssat,
        uint32_t kn0, uint32_t kn1, int S, int inS, int SS,
        int blo, int bhi, int bw, int bwp,
        float cos_t, float sin_t, float sc, float ctr, int N, int NCH, int X8,
        int NB1, int NTOT2, int Gtot,
        float4* __restrict__ out,
        float h0, float h1, float h2, float h3, float h4, float h5, float h6, float h7) {
  int b = blockIdx.x;

  if (b < nbRes) {
    // ---- resize-partials role: gray partial sums only (bit-identical, R13-verified) ----
    __shared__ double sh[256];
    int t = b * 256 + threadIdx.x;
    double g = 0.0;
    if (t < SS) {
      int y = t / S, x = t - y * S;
      float rgb[3];
      resize_rgb(adv, inS, S, x, y, bmul, rgb);
      g = (double)(0.2989f * rgb[0] + 0.587f * rgb[1] + 0.114f * rgb[2]);
    }
    sh[threadIdx.x] = g;
    __syncthreads();
    for (int s2 = 128; s2 > 0; s2 >>= 1) {
      if (threadIdx.x < s2) sh[threadIdx.x] += sh[threadIdx.x + s2];
      __syncthreads();
    }
    if (threadIdx.x == 0) part[b] = sh[0];
    return;
  }

  // ---- Bresenham interleave between hash (NB1) and zero (NTOT2-NB1) roles ----
  int b2 = b - nbRes;
  long long tt = (long long)b2 * NB1;
  int h_before = (int)(tt / NTOT2);
  int h_incl   = (int)((tt + NB1) / NTOT2);
  bool is_hash = (h_incl > h_before);

  if (!is_hash) {
    int zb = b2 - h_before;
    int g = zb * 256 + (int)threadIdx.x;
    zero_role(g, Gtot, N, S, X8, blo, bhi, out, h0, h1, h2, h3, h4, h5, h6, h7);
    return;
  }

  // ---- hash role: thread = (b1 pixel, n-chunk). Taps+color computed ONCE, reused
  //      across NCHUNK n values. Accumulation order per (n,u,c) identical to R13. ----
  int idx = h_before * 256 + threadIdx.x;
  int BWW = bw * bw;
  if (idx >= BWW * NCH) return;
  int px = idx % bw;
  int t2 = idx / bw;
  int py = t2 % bw;
  int ch = t2 / bw;
  int n0 = ch * NCHUNK;
  int n1 = min(n0 + NCHUNK, N);

  int xt = blo + px, yt = blo + py;
  float dx = (float)xt - ctr, dy = (float)yt - ctr;
  float sx = (cos_t * dx + sin_t * dy) / sc + ctr;
  float sy = (-sin_t * dx + cos_t * dy) / sc + ctr;
  float x0f = floorf(sx), y0f = floorf(sy);
  float wx1 = sx - x0f, wy1 = sy - y0f;
  float wx0 = 1.f - wx1, wy0 = 1.f - wy1;
  float Wm1 = (float)(S - 1);
  float xtf[4] = {x0f, x0f + 1.f, x0f, x0f + 1.f};
  float ytf[4] = {y0f, y0f, y0f + 1.f, y0f + 1.f};
  float wt[4]  = {wy0 * wx0, wy0 * wx1, wy1 * wx0, wy1 * wx1};
  float oms = 1.0f - ssat;

  // precompute per-tap colored values (m-free) + validity, ONCE
  bool  tvalid[4];
  float colored[4][3];
  uint32_t spv[4];
  float accW = 0.f;
#pragma unroll
  for (int u = 0; u < 4; ++u) {
    tvalid[u] = (xtf[u] >= 0.f) && (xtf[u] <= Wm1) && (ytf[u] >= 0.f) && (ytf[u] <= Wm1);
    if (!tvalid[u]) { spv[u] = 0; colored[u][0] = colored[u][1] = colored[u][2] = 0.f; continue; }
    int ix = (int)xtf[u], iy = (int)ytf[u];
    int sp = iy * S + ix;
    spv[u] = (uint32_t)sp;
    float p[3];
    resize_rgb(adv, inS, S, ix, iy, bmul, p);
    float gray_p = 0.2989f * p[0] + 0.587f * p[1] + 0.114f * p[2];
#pragma unroll
    for (int c = 0; c < 3; ++c)
      colored[u][c] = cc * (ssat * p[c] + oms * gray_p);
    accW += wt[u];
  }

  for (int n = n0; n < n1; ++n) {
    float acc[3] = {0.f, 0.f, 0.f};
    uint32_t nbase = (uint32_t)(n * 3) * (uint32_t)SS;
#pragma unroll
    for (int u = 0; u < 4; ++u) {
      if (!tvalid[u]) continue;            // contributes exactly 0 (incl. m-term)
      uint32_t idx0 = nbase + spv[u];
#pragma unroll
      for (int c = 0; c < 3; ++c) {
        uint32_t bits = tf_bits32(kn0, kn1, idx0 + (uint32_t)(c * SS));
        acc[c] += wt[u] * (colored[u][c] + noise_from_bits(bits));
      }
    }
    b1[((size_t)n * bw + py) * bwp + px] = make_float4(acc[0], acc[1], acc[2], accW);
  }
}

// ================= Kernel 2: interior perspective sample; adds deferred m-term (R13-verified)
__global__ void __launch_bounds__(256)
k_out_in2(const float4* __restrict__ b1, float4* __restrict__ out,
          const double* __restrict__ part, int nbRes, float Km,
          int S, int SS, int X8, int blo, int bhi, int bw, int bwp,
          int ylo, int rows, int glo, int gcnt, int totalInt,
          float h0, float h1, float h2, float h3, float h4, float h5, float h6, float h7) {
  __shared__ double sh[256];
  double a = 0.0;
  for (int i = threadIdx.x; i < nbRes; i += 256) a += part[i];
  sh[threadIdx.x] = a;
  __syncthreads();
  for (int s2 = 128; s2 > 0; s2 >>= 1) {
    if (threadIdx.x < s2) sh[threadIdx.x] += sh[threadIdx.x + s2];
    __syncthreads();
  }
  float m = (float)(sh[0] / (double)SS);
  float Kmm = Km * m;

  int tid = blockIdx.x * 256 + threadIdx.x;
  if (tid >= totalInt) return;
  int x8 = glo + tid % gcnt;
  int t2 = tid / gcnt;
  int y  = ylo + t2 % rows;
  int n  = t2 / rows;

  int X4 = X8 * 2;
  float yo  = (float)y + 0.5f;
  float xo0 = (float)(x8 * 8) + 0.5f;
  float xo7 = xo0 + 7.0f;
  float den0 = h6 * xo0 + h7 * yo + 1.0f;
  float den7 = h6 * xo7 + h7 * yo + 1.0f;
  float psx0 = (h0 * xo0 + h1 * yo + h2) / den0 - 0.5f;
  float psy0 = (h3 * xo0 + h4 * yo + h5) / den0 - 0.5f;
  float psx7 = (h0 * xo7 + h1 * yo + h2) / den7 - 0.5f;
  float psy7 = (h3 * xo7 + h4 * yo + h5) / den7 - 0.5f;
  float lox = fminf(psx0, psx7), hix = fmaxf(psx0, psx7);
  float loy = fminf(psy0, psy7), hiy = fmaxf(psy0, psy7);
  float bl = (float)blo - 1.5f, bh = (float)bhi + 1.5f;
  bool exterior = (den0 > 0.0f) && (den7 > 0.0f) &&
                  (hix < bl || lox > bh || hiy < bl || loy > bh);
  if (exterior) return;                    // zero role (K1) already wrote this group

  float acc[3][8];
#pragma unroll
  for (int c = 0; c < 3; ++c)
#pragma unroll
    for (int j = 0; j < 8; ++j) acc[c][j] = 0.f;

  float Wm1 = (float)(S - 1);
#pragma unroll
  for (int j = 0; j < 8; ++j) {
    float xo = (float)(x8 * 8 + j) + 0.5f;
    float den = h6 * xo + h7 * yo + 1.0f;
    float psx = (h0 * xo + h1 * yo + h2) / den - 0.5f;
    float psy = (h3 * xo + h4 * yo + h5) / den - 0.5f;
    float x0f = floorf(psx), y0f = floorf(psy);
    float wx1 = psx - x0f, wy1 = psy - y0f;
    float wx0 = 1.f - wx1, wy0 = 1.f - wy1;
    float xtf[4] = {x0f, x0f + 1.f, x0f, x0f + 1.f};
    float ytf[4] = {y0f, y0f, y0f + 1.f, y0f + 1.f};
    float wtp[4] = {wy0 * wx0, wy0 * wx1, wy1 * wx0, wy1 * wx1};
#pragma unroll
    for (int u = 0; u < 4; ++u) {
      bool valid = (xtf[u] >= 0.f) && (xtf[u] <= Wm1) && (ytf[u] >= 0.f) && (ytf[u] <= Wm1);
      if (!valid) continue;
      int ix = (int)xtf[u] - blo;
      int iy = (int)ytf[u] - blo;
      if (ix < 0 || ix >= bw || iy < 0 || iy >= bw) continue;   // batch1 == 0 there
      float4 v = b1[((size_t)n * bw + iy) * bwp + ix];
      float mterm = Kmm * v.w;
      acc[0][j] += wtp[u] * (v.x + mterm);
      acc[1][j] += wtp[u] * (v.y + mterm);
      acc[2][j] += wtp[u] * (v.z + mterm);
    }
  }

  size_t obase = ((size_t)(n * 3) * S + y) * X4 + x8 * 2;
  size_t ostride = (size_t)S * X4;
#pragma unroll
  for (int c = 0; c < 3; ++c) {
    float4 v0, v1;
    v0.x = fminf(fmaxf(acc[c][0], 0.0f), 0.99f);
    v0.y = fminf(fmaxf(acc[c][1], 0.0f), 0.99f);
    v0.z = fminf(fmaxf(acc[c][2], 0.0f), 0.99f);
    v0.w = fminf(fmaxf(acc[c][3], 0.0f), 0.99f);
    v1.x = fminf(fmaxf(acc[c][4], 0.0f), 0.99f);
    v1.y = fminf(fmaxf(acc[c][5], 0.0f), 0.99f);
    v1.z = fminf(fmaxf(acc[c][6], 0.0f), 0.99f);
    v1.w = fminf(fmaxf(acc[c][7], 0.0f), 0.99f);
    out[obase + (size_t)c * ostride]     = v0;
    out[obase + (size_t)c * ostride + 1] = v1;
  }
}

// ================= Host helpers =================
static float bits_to_u01_host(uint32_t bits) {
  uint32_t fb = (bits >> 9) | 0x3f800000u;
  float f;
  std::memcpy(&f, &fb, 4);
  return f - 1.0f;
}

static float host_uniform(uint32_t k0, uint32_t k1, float mn, float mx) {
  uint32_t bits = tf_bits32(k0, k1, 0u);
  float f = bits_to_u01_host(bits);
  float d = mx - mn;
  float t = f * d;
  float v = t + mn;
  return v < mn ? mn : v;
}

static void solve8(float A[8][8], float b[8], float x[8]) {
  for (int k = 0; k < 8; ++k) {
    int piv = k;
    float amax = fabsf(A[k][k]);
    for (int i = k + 1; i < 8; ++i) {
      float v = fabsf(A[i][k]);
      if (v > amax) { amax = v; piv = i; }
    }
    if (piv != k) {
      for (int j = 0; j < 8; ++j) { float t = A[k][j]; A[k][j] = A[piv][j]; A[piv][j] = t; }
      float t = b[k]; b[k] = b[piv]; b[piv] = t;
    }
    for (int i = k + 1; i < 8; ++i) {
      float l = A[i][k] / A[k][k];
      A[i][k] = l;
      for (int j = k + 1; j < 8; ++j) A[i][j] -= l * A[k][j];
      b[i] -= l * b[k];
    }
  }
  for (int i = 7; i >= 0; --i) {
    float s = b[i];
    for (int j = i + 1; j < 8; ++j) s -= A[i][j] * x[j];
    x[i] = s / A[i][i];
  }
}

extern "C" void kernel_launch(void* const* d_in, const int* in_sizes, int n_in,
                              void* d_out, int out_size, void* d_ws, size_t ws_size,
                              hipStream_t stream) {
  const float* adv = (const float*)d_in[0];
  float* out = (float*)d_out;

  // ---- shapes ----
  int inS = (int)llround(sqrt((double)in_sizes[0] / 3.0));   // 300
  int N   = in_sizes[1] / 5;                                  // 112
  if (N <= 0) N = 112;
  int S   = (int)llround(sqrt((double)out_size / (3.0 * N))); // 416
  int SS  = S * S;

  // ---- PRNG: partitionable. key(42)=(0,42); foldlike split(7): K_i = tf(key,(0,i)) ----
  uint32_t K[7][2];
  for (int i = 0; i < 7; ++i)
    tf2x32(0u, 42u, 0u, (uint32_t)i, K[i][0], K[i][1]);
  // order: kb, kc, ks, kn, ka, ksc, kp

  float bmul = host_uniform(K[0][0], K[0][1], 0.8f, 1.1f);
  float cc   = host_uniform(K[1][0], K[1][1], 0.8f, 1.1f);
  float ssat = host_uniform(K[2][0], K[2][1], 0.8f, 1.1f);
  float adeg = host_uniform(K[4][0], K[4][1], -45.f, 45.f);
  float theta = adeg * (float)(M_PI / 180.0);
  float sc   = host_uniform(K[5][0], K[5][1], 0.1f, 0.16f);
  float cos_t = cosf(theta), sin_t = sinf(theta);

  // deferred-mean coefficient: pfv[c] = cc*(ssat*p + oms*gray_p) + Km*m
  float omc = 1.0f - cc, oms = 1.0f - ssat;
  float wsum = 0.2989f + 0.587f + 0.114f;
  float Km = omc * (ssat + oms * wsum);

  // ---- randint(kp, (8,), 0, dmax+1): k1,k2 = split(kp); higher=bits(k1); lower=bits(k2) ----
  int dmax = (int)(0.6 * (double)(S / 2));        // 124
  uint32_t span = (uint32_t)(dmax + 1);           // 125
  uint32_t mult = ((65536u % span) * (65536u % span)) % span;
  uint32_t kp1[2], kp2[2];
  tf2x32(K[6][0], K[6][1], 0u, 0u, kp1[0], kp1[1]);
  tf2x32(K[6][0], K[6][1], 0u, 1u, kp2[0], kp2[1]);
  float r[8];
  for (int i = 0; i < 8; ++i) {
    uint32_t hi = tf_bits32(kp1[0], kp1[1], (uint32_t)i);
    uint32_t lo = tf_bits32(kp2[0], kp2[1], (uint32_t)i);
    uint32_t v = ((hi % span) * mult + (lo % span)) % span;
    r[i] = (float)v;
  }

  // ---- homography: T(end)=start ----
  float w = (float)(S - 1);
  float ex[4] = {r[0], w - r[2], w - r[4], r[6]};
  float ey[4] = {r[1], r[3], w - r[5], w - r[7]};
  float px4[4] = {0.f, w, w, 0.f};
  float py4[4] = {0.f, 0.f, w, w};
  float A[8][8];
  float rhs[8];
  for (int i = 0; i < 4; ++i) {
    A[i][0] = ex[i]; A[i][1] = ey[i]; A[i][2] = 1.f;
    A[i][3] = 0.f;   A[i][4] = 0.f;   A[i][5] = 0.f;
    A[i][6] = -px4[i] * ex[i]; A[i][7] = -px4[i] * ey[i];
    rhs[i] = px4[i];
    A[4 + i][0] = 0.f; A[4 + i][1] = 0.f; A[4 + i][2] = 0.f;
    A[4 + i][3] = ex[i]; A[4 + i][4] = ey[i]; A[4 + i][5] = 1.f;
    A[4 + i][6] = -py4[i] * ex[i]; A[4 + i][7] = -py4[i] * ey[i];
    rhs[4 + i] = py4[i];
  }
  float h[8];
  solve8(A, rhs, h);

  // ---- bbox of batch1 support ----
  float ctr = (float)(S - 1) * 0.5f;
  float a_half = (ctr + 2.0f) * sc;
  float bbh = a_half * (fabsf(cos_t) + fabsf(sin_t)) + 3.0f;
  int blo = (int)floorf(ctr - bbh); if (blo < 0) blo = 0;
  int bhi = (int)ceilf(ctr + bbh);  if (bhi > S - 1) bhi = S - 1;
  int bw = bhi - blo + 1;
  int bwp = (bw + 15) & ~15;

  // ---- host-side conservative interior bbox over (y, x8) groups ----
  int X8 = S / 8;
  int ylo = S, yhi = -1, glo = X8, ghi = -1;
  {
    double H0 = h[0], H1 = h[1], H2 = h[2], H3 = h[3], H4 = h[4], H5 = h[5], H6 = h[6], H7 = h[7];
    double bl = (double)blo - 3.0, bh = (double)bhi + 3.0;
    for (int y = 0; y < S; ++y) {
      double yo = y + 0.5;
      for (int g = 0; g < X8; ++g) {
        double xo0 = g * 8 + 0.5, xo7 = xo0 + 7.0;
        double den0 = H6 * xo0 + H7 * yo + 1.0;
        double den7 = H6 * xo7 + H7 * yo + 1.0;
        bool ext;
        if (den0 > 0.0 && den7 > 0.0) {
          double psx0 = (H0 * xo0 + H1 * yo + H2) / den0 - 0.5;
          double psy0 = (H3 * xo0 + H4 * yo + H5) / den0 - 0.5;
          double psx7 = (H0 * xo7 + H1 * yo + H2) / den7 - 0.5;
          double psy7 = (H3 * xo7 + H4 * yo + H5) / den7 - 0.5;
          double lox = fmin(psx0, psx7), hix = fmax(psx0, psx7);
          double loy = fmin(psy0, psy7), hiy = fmax(psy0, psy7);
          ext = (hix < bl || lox > bh || hiy < bl || loy > bh);
        } else {
          ext = false;
        }
        if (!ext) {
          if (y < ylo) ylo = y;
          if (y > yhi) yhi = y;
          if (g < glo) glo = g;
          if (g > ghi) ghi = g;
        }
      }
    }
  }
  int rows = (yhi >= ylo) ? (yhi - ylo + 1) : 0;
  int gcnt = (ghi >= glo) ? (ghi - glo + 1) : 0;

  // ---- workspace layout: part (8 KB region) + b1 float4[N][bw][bwp] ----
  double* part = (double*)d_ws;
  float4* b1   = (float4*)((char*)d_ws + 8192);

  int nbRes = (SS + 255) / 256;                 // 677
  int Gtot  = N * S * X8;
  int NZ    = (Gtot + 255) / 256;               // zero blocks
  int NCH   = (N + NCHUNK - 1) / NCHUNK;        // n-chunks (14 for N=112)
  int NB1   = (bw * bw * NCH + 255) / 256;      // hash blocks (n-amortized)
  int NTOT2 = NB1 + NZ;

  // K1: resize-partials + interleaved (hash | zero)
  k_fused<<<nbRes + NTOT2, 256, 0, stream>>>(
      adv, b1, part, nbRes, bmul, cc, ssat,
      K[3][0], K[3][1], S, inS, SS, blo, bhi, bw, bwp,
      cos_t, sin_t, sc, ctr, N, NCH, X8, NB1, NTOT2, Gtot, (float4*)out,
      h[0], h[1], h[2], h[3], h[4], h[5], h[6], h[7]);

  // K2: interior-only + deferred m-term
  int totalInt = N * rows * gcnt;
  if (totalInt > 0) {
    k_out_in2<<<(totalInt + 255) / 256, 256, 0, stream>>>(
        b1, (float4*)out, part, nbRes, Km,
        S, SS, X8, blo, bhi, bw, bwp,
        ylo, rows, glo, gcnt, totalInt,
        h[0], h[1], h[2], h[3], h[4], h[5], h[6], h[7]);
  }
}

// Round 15
// 74.743 us; speedup vs baseline: 1.2745x; 1.2745x over previous
//
#include <hip/hip_runtime.h>
#include <cstdint>
#include <cstring>
#include <cmath>

// ========== Threefry2x32 (JAX, 20 rounds) — core verified on-device via KAT (R3) ==========
__host__ __device__ static inline uint32_t rotl32(uint32_t x, int r) {
  return (x << r) | (x >> (32 - r));
}

__host__ __device__ static inline void tf2x32(uint32_t k0, uint32_t k1,
                                              uint32_t c0, uint32_t c1,
                                              uint32_t& o0, uint32_t& o1) {
  const uint32_t ks2 = 0x1BD11BDAu ^ k0 ^ k1;
  uint32_t x0 = c0 + k0;
  uint32_t x1 = c1 + k1;
#define TF_QR(r) { x0 += x1; x1 = rotl32(x1, (r)); x1 ^= x0; }
  TF_QR(13) TF_QR(15) TF_QR(26) TF_QR(6)
  x0 += k1;  x1 += ks2 + 1u;
  TF_QR(17) TF_QR(29) TF_QR(16) TF_QR(24)
  x0 += ks2; x1 += k0 + 2u;
  TF_QR(13) TF_QR(15) TF_QR(26) TF_QR(6)
  x0 += k0;  x1 += k1 + 3u;
  TF_QR(17) TF_QR(29) TF_QR(16) TF_QR(24)
  x0 += k1;  x1 += ks2 + 4u;
  TF_QR(13) TF_QR(15) TF_QR(26) TF_QR(6)
  x0 += ks2; x1 += k0 + 5u;
#undef TF_QR
  o0 = x0; o1 = x1;
}

// partitionable 32-bit draw at flat index i: counter (0, i), bits = o0 ^ o1
__host__ __device__ static inline uint32_t tf_bits32(uint32_t k0, uint32_t k1, uint32_t i) {
  uint32_t a, b;
  tf2x32(k0, k1, 0u, i, a, b);
  return a ^ b;
}

__device__ static inline float noise_from_bits(uint32_t bits) {
  uint32_t fb = (bits >> 9) | 0x3f800000u;
  float f = __uint_as_float(fb) - 1.0f;
  float v = f * 2.0f - 1.0f;
  v = fmaxf(-1.0f, v);
  return 0.15f * v;
}

// ========== Shared zero role (verified R10-R12): group g -> exterior test, 6x float4 zeros ==
__device__ static inline void zero_role(int g, int Gtot, int N, int S, int X8,
                                        int blo, int bhi, float4* __restrict__ out,
                                        float h0, float h1, float h2, float h3,
                                        float h4, float h5, float h6, float h7) {
  if (g >= Gtot) return;
  int x8 = g % X8;
  int t2 = g / X8;
  int y  = t2 % S;
  int n  = t2 / S;
  float yo  = (float)y + 0.5f;
  float xo0 = (float)(x8 * 8) + 0.5f;
  float xo7 = xo0 + 7.0f;
  float den0 = h6 * xo0 + h7 * yo + 1.0f;
  float den7 = h6 * xo7 + h7 * yo + 1.0f;
  float psx0 = (h0 * xo0 + h1 * yo + h2) / den0 - 0.5f;
  float psy0 = (h3 * xo0 + h4 * yo + h5) / den0 - 0.5f;
  float psx7 = (h0 * xo7 + h1 * yo + h2) / den7 - 0.5f;
  float psy7 = (h3 * xo7 + h4 * yo + h5) / den7 - 0.5f;
  float lox = fminf(psx0, psx7), hix = fmaxf(psx0, psx7);
  float loy = fminf(psy0, psy7), hiy = fmaxf(psy0, psy7);
  float bl = (float)blo - 1.5f, bh = (float)bhi + 1.5f;
  bool exterior = (den0 > 0.0f) && (den7 > 0.0f) &&
                  (hix < bl || lox > bh || hiy < bl || loy > bh);
  if (!exterior) return;                   // interior role writes this group
  int X4 = X8 * 2;
  size_t obase = ((size_t)(n * 3) * S + y) * X4 + x8 * 2;
  size_t ostride = (size_t)S * X4;
  float4 z = make_float4(0.f, 0.f, 0.f, 0.f);
  out[obase]                = z;
  out[obase + 1]            = z;
  out[obase + ostride]      = z;
  out[obase + ostride + 1]  = z;
  out[obase + 2 * ostride]     = z;
  out[obase + 2 * ostride + 1] = z;
}

// ================= Kernel A: resize (blocks < nbA, p1 stored float4-interleaved) + zeros ===
__global__ void __launch_bounds__(256)
k_resize_z(const float* __restrict__ src, float4* __restrict__ p1,
           double* __restrict__ part, float bmul, int S, int inS, int SS, int nbA,
           int zstart, int Gtot, int N, int X8, int blo, int bhi,
           float4* __restrict__ out,
           float h0, float h1, float h2, float h3, float h4, float h5, float h6, float h7) {
  if ((int)blockIdx.x >= nbA) {
    int g = zstart + ((int)blockIdx.x - nbA) * 256 + (int)threadIdx.x;
    zero_role(g, Gtot, N, S, X8, blo, bhi, out, h0, h1, h2, h3, h4, h5, h6, h7);
    return;
  }
  __shared__ double sh[256];
  int t = blockIdx.x * 256 + threadIdx.x;
  double g = 0.0;
  if (t < SS) {
    int y = t / S, x = t - y * S;
    float fs = (float)inS / (float)S;
    float fy = ((float)y + 0.5f) * fs - 0.5f;
    float fx = ((float)x + 0.5f) * fs - 0.5f;
    float y0f = floorf(fy), x0f = floorf(fx);
    float ty = fy - y0f, tx = fx - x0f;
    int y0 = (int)y0f, x0 = (int)x0f;
    int y1 = y0 + 1, x1 = x0 + 1;
    y0 = min(max(y0, 0), inS - 1); y1 = min(max(y1, 0), inS - 1);
    x0 = min(max(x0, 0), inS - 1); x1 = min(max(x1, 0), inS - 1);
    float w00 = (1.f - ty) * (1.f - tx), w01 = (1.f - ty) * tx;
    float w10 = ty * (1.f - tx),         w11 = ty * tx;
    float rgb[3];
    for (int c = 0; c < 3; ++c) {
      const float* pc = src + (size_t)c * inS * inS;
      float v = pc[y0 * inS + x0] * w00 + pc[y0 * inS + x1] * w01 +
                pc[y1 * inS + x0] * w10 + pc[y1 * inS + x1] * w11;
      v *= bmul;
      rgb[c] = v;
    }
    p1[t] = make_float4(rgb[0], rgb[1], rgb[2], 0.0f);
    g = (double)(0.2989f * rgb[0] + 0.587f * rgb[1] + 0.114f * rgb[2]);
  }
  sh[threadIdx.x] = g;
  __syncthreads();
  for (int s2 = 128; s2 > 0; s2 >>= 1) {
    if (threadIdx.x < s2) sh[threadIdx.x] += sh[threadIdx.x + s2];
    __syncthreads();
  }
  if (threadIdx.x == 0) part[blockIdx.x] = sh[0];
}

// ================= Kernel B: Bresenham-interleaved batch1c-hash ∥ zero slice =============
// Hash role loads p1 as ONE float4 per tap (same f32 values, 1 line vs 3-6 lines).
__global__ void __launch_bounds__(256)
k_combined(const float4* __restrict__ p1, float* __restrict__ b1,
           const double* __restrict__ part, int nb,
           float cc, float ssat,
           uint32_t kn0, uint32_t kn1, int S, int SS, int blo, int bhi, int bw, int bwp,
           float cos_t, float sin_t, float sc, float ctr, int N, int X8,
           int NB1, int NTOT, int zstart, int Gtot,
           float4* __restrict__ out,
           float h0, float h1, float h2, float h3, float h4, float h5, float h6, float h7) {
  int b = blockIdx.x;
  long long tt = (long long)b * NB1;
  int h_before = (int)(tt / NTOT);
  int h_incl   = (int)((tt + NB1) / NTOT);
  bool is_hash = (h_incl > h_before);

  if (!is_hash) {
    int zb = b - h_before;
    int g = zstart + zb * 256 + (int)threadIdx.x;
    zero_role(g, Gtot, N, S, X8, blo, bhi, out, h0, h1, h2, h3, h4, h5, h6, h7);
    return;
  }

  // ---- hash role: batch1c (verified R6/R7; p1 float4 layout per R12) ----
  __shared__ double sh[256];
  double a = 0.0;
  for (int i = threadIdx.x; i < nb; i += 256) a += part[i];
  sh[threadIdx.x] = a;
  __syncthreads();
  for (int s2 = 128; s2 > 0; s2 >>= 1) {
    if (threadIdx.x < s2) sh[threadIdx.x] += sh[threadIdx.x + s2];
    __syncthreads();
  }
  float m = (float)(sh[0] / (double)SS);

  int idx = h_before * 256 + threadIdx.x;
  if (idx >= bw * bw * N) return;
  int px = idx % bw;
  int t2 = idx / bw;
  int py = t2 % bw;
  int n  = t2 / bw;

  int xt = blo + px, yt = blo + py;
  float dx = (float)xt - ctr, dy = (float)yt - ctr;
  float sx = (cos_t * dx + sin_t * dy) / sc + ctr;
  float sy = (-sin_t * dx + cos_t * dy) / sc + ctr;
  float x0f = floorf(sx), y0f = floorf(sy);
  float wx1 = sx - x0f, wy1 = sy - y0f;
  float wx0 = 1.f - wx1, wy0 = 1.f - wy1;
  float Wm1 = (float)(S - 1);
  float xtf[4] = {x0f, x0f + 1.f, x0f, x0f + 1.f};
  float ytf[4] = {y0f, y0f, y0f + 1.f, y0f + 1.f};
  float wt[4]  = {wy0 * wx0, wy0 * wx1, wy1 * wx0, wy1 * wx1};
  float acc[3] = {0.f, 0.f, 0.f};
  uint32_t nbase = (uint32_t)(n * 3) * (uint32_t)SS;
  float omc = 1.0f - cc, oms = 1.0f - ssat;
#pragma unroll
  for (int u = 0; u < 4; ++u) {
    bool valid = (xtf[u] >= 0.f) && (xtf[u] <= Wm1) && (ytf[u] >= 0.f) && (ytf[u] <= Wm1);
    if (!valid) continue;                  // contributes exactly 0
    int ix = (int)xtf[u], iy = (int)ytf[u];
    int sp = iy * S + ix;
    float4 p = p1[sp];                     // one dwordx4: r,g,b,(pad)
    float r2 = cc * p.x + omc * m;
    float g2 = cc * p.y + omc * m;
    float b2 = cc * p.z + omc * m;
    float gray = 0.2989f * r2 + 0.587f * g2 + 0.114f * b2;
    float pfv[3];
    pfv[0] = ssat * r2 + oms * gray;
    pfv[1] = ssat * g2 + oms * gray;
    pfv[2] = ssat * b2 + oms * gray;
    uint32_t idx0 = nbase + (uint32_t)sp;
#pragma unroll
    for (int c = 0; c < 3; ++c) {
      uint32_t bits = tf_bits32(kn0, kn1, idx0 + (uint32_t)(c * SS));
      acc[c] += wt[u] * (pfv[c] + noise_from_bits(bits));
    }
  }
#pragma unroll
  for (int c = 0; c < 3; ++c)
    b1[(((size_t)n * 3 + c) * bw + py) * bwp + px] = acc[c];
}

// ================= Kernel C: interior perspective sample (blocks < nbInt) + zero slice ====
__global__ void __launch_bounds__(256)
k_out_in_z(const float* __restrict__ b1, float4* __restrict__ out,
           int S, int X8, int blo, int bhi, int bw, int bwp,
           int ylo, int rows, int glo, int gcnt, int totalInt, int nbInt,
           int zstart, int Gtot, int N,
           float h0, float h1, float h2, float h3, float h4, float h5, float h6, float h7) {
  if ((int)blockIdx.x >= nbInt) {
    int g = zstart + ((int)blockIdx.x - nbInt) * 256 + (int)threadIdx.x;
    zero_role(g, Gtot, N, S, X8, blo, bhi, out, h0, h1, h2, h3, h4, h5, h6, h7);
    return;
  }
  int tid = blockIdx.x * 256 + threadIdx.x;
  if (tid >= totalInt) return;
  int x8 = glo + tid % gcnt;
  int t2 = tid / gcnt;
  int y  = ylo + t2 % rows;
  int n  = t2 / rows;

  int X4 = X8 * 2;
  float yo  = (float)y + 0.5f;
  float xo0 = (float)(x8 * 8) + 0.5f;
  float xo7 = xo0 + 7.0f;
  float den0 = h6 * xo0 + h7 * yo + 1.0f;
  float den7 = h6 * xo7 + h7 * yo + 1.0f;
  float psx0 = (h0 * xo0 + h1 * yo + h2) / den0 - 0.5f;
  float psy0 = (h3 * xo0 + h4 * yo + h5) / den0 - 0.5f;
  float psx7 = (h0 * xo7 + h1 * yo + h2) / den7 - 0.5f;
  float psy7 = (h3 * xo7 + h4 * yo + h5) / den7 - 0.5f;
  float lox = fminf(psx0, psx7), hix = fmaxf(psx0, psx7);
  float loy = fminf(psy0, psy7), hiy = fmaxf(psy0, psy7);
  float bl = (float)blo - 1.5f, bh = (float)bhi + 1.5f;
  bool exterior = (den0 > 0.0f) && (den7 > 0.0f) &&
                  (hix < bl || lox > bh || hiy < bl || loy > bh);
  if (exterior) return;                    // zero roles already wrote this group

  float acc[3][8];
#pragma unroll
  for (int c = 0; c < 3; ++c)
#pragma unroll
    for (int j = 0; j < 8; ++j) acc[c][j] = 0.f;

  float Wm1 = (float)(S - 1);
#pragma unroll
  for (int j = 0; j < 8; ++j) {
    float xo = (float)(x8 * 8 + j) + 0.5f;
    float den = h6 * xo + h7 * yo + 1.0f;
    float psx = (h0 * xo + h1 * yo + h2) / den - 0.5f;
    float psy = (h3 * xo + h4 * yo + h5) / den - 0.5f;
    float x0f = floorf(psx), y0f = floorf(psy);
    float wx1 = psx - x0f, wy1 = psy - y0f;
    float wx0 = 1.f - wx1, wy0 = 1.f - wy1;
    float xtf[4] = {x0f, x0f + 1.f, x0f, x0f + 1.f};
    float ytf[4] = {y0f, y0f, y0f + 1.f, y0f + 1.f};
    float wt[4]  = {wy0 * wx0, wy0 * wx1, wy1 * wx0, wy1 * wx1};
#pragma unroll
    for (int u = 0; u < 4; ++u) {
      bool valid = (xtf[u] >= 0.f) && (xtf[u] <= Wm1) && (ytf[u] >= 0.f) && (ytf[u] <= Wm1);
      if (!valid) continue;
      int ix = (int)xtf[u] - blo;
      int iy = (int)ytf[u] - blo;
      if (ix < 0 || ix >= bw || iy < 0 || iy >= bw) continue;   // batch1 == 0 there
#pragma unroll
      for (int c = 0; c < 3; ++c)
        acc[c][j] += wt[u] * b1[(((size_t)n * 3 + c) * bw + iy) * bwp + ix];
    }
  }

  size_t obase = ((size_t)(n * 3) * S + y) * X4 + x8 * 2;
  size_t ostride = (size_t)S * X4;
#pragma unroll
  for (int c = 0; c < 3; ++c) {
    float4 v0, v1;
    v0.x = fminf(fmaxf(acc[c][0], 0.0f), 0.99f);
    v0.y = fminf(fmaxf(acc[c][1], 0.0f), 0.99f);
    v0.z = fminf(fmaxf(acc[c][2], 0.0f), 0.99f);
    v0.w = fminf(fmaxf(acc[c][3], 0.0f), 0.99f);
    v1.x = fminf(fmaxf(acc[c][4], 0.0f), 0.99f);
    v1.y = fminf(fmaxf(acc[c][5], 0.0f), 0.99f);
    v1.z = fminf(fmaxf(acc[c][6], 0.0f), 0.99f);
    v1.w = fminf(fmaxf(acc[c][7], 0.0f), 0.99f);
    out[obase + (size_t)c * ostride]     = v0;
    out[obase + (size_t)c * ostride + 1] = v1;
  }
}

// ================= Host helpers =================
static float bits_to_u01_host(uint32_t bits) {
  uint32_t fb = (bits >> 9) | 0x3f800000u;
  float f;
  std::memcpy(&f, &fb, 4);
  return f - 1.0f;
}

static float host_uniform(uint32_t k0, uint32_t k1, float mn, float mx) {
  uint32_t bits = tf_bits32(k0, k1, 0u);
  float f = bits_to_u01_host(bits);
  float d = mx - mn;
  float t = f * d;
  float v = t + mn;
  return v < mn ? mn : v;
}

static void solve8(float A[8][8], float b[8], float x[8]) {
  for (int k = 0; k < 8; ++k) {
    int piv = k;
    float amax = fabsf(A[k][k]);
    for (int i = k + 1; i < 8; ++i) {
      float v = fabsf(A[i][k]);
      if (v > amax) { amax = v; piv = i; }
    }
    if (piv != k) {
      for (int j = 0; j < 8; ++j) { float t = A[k][j]; A[k][j] = A[piv][j]; A[piv][j] = t; }
      float t = b[k]; b[k] = b[piv]; b[piv] = t;
    }
    for (int i = k + 1; i < 8; ++i) {
      float l = A[i][k] / A[k][k];
      A[i][k] = l;
      for (int j = k + 1; j < 8; ++j) A[i][j] -= l * A[k][j];
      b[i] -= l * b[k];
    }
  }
  for (int i = 7; i >= 0; --i) {
    float s = b[i];
    for (int j = i + 1; j < 8; ++j) s -= A[i][j] * x[j];
    x[i] = s / A[i][i];
  }
}

extern "C" void kernel_launch(void* const* d_in, const int* in_sizes, int n_in,
                              void* d_out, int out_size, void* d_ws, size_t ws_size,
                              hipStream_t stream) {
  const float* adv = (const float*)d_in[0];
  float* out = (float*)d_out;

  // ---- shapes ----
  int inS = (int)llround(sqrt((double)in_sizes[0] / 3.0));   // 300
  int N   = in_sizes[1] / 5;                                  // 112
  if (N <= 0) N = 112;
  int S   = (int)llround(sqrt((double)out_size / (3.0 * N))); // 416
  int SS  = S * S;

  // ---- PRNG: partitionable. key(42)=(0,42); foldlike split(7): K_i = tf(key,(0,i)) ----
  uint32_t K[7][2];
  for (int i = 0; i < 7; ++i)
    tf2x32(0u, 42u, 0u, (uint32_t)i, K[i][0], K[i][1]);
  // order: kb, kc, ks, kn, ka, ksc, kp

  float bmul = host_uniform(K[0][0], K[0][1], 0.8f, 1.1f);
  float cc   = host_uniform(K[1][0], K[1][1], 0.8f, 1.1f);
  float ssat = host_uniform(K[2][0], K[2][1], 0.8f, 1.1f);
  float adeg = host_uniform(K[4][0], K[4][1], -45.f, 45.f);
  float theta = adeg * (float)(M_PI / 180.0);
  float sc   = host_uniform(K[5][0], K[5][1], 0.1f, 0.16f);
  float cos_t = cosf(theta), sin_t = sinf(theta);

  // ---- randint(kp, (8,), 0, dmax+1): k1,k2 = split(kp); higher=bits(k1); lower=bits(k2) ----
  int dmax = (int)(0.6 * (double)(S / 2));        // 124
  uint32_t span = (uint32_t)(dmax + 1);           // 125
  uint32_t mult = ((65536u % span) * (65536u % span)) % span;
  uint32_t kp1[2], kp2[2];
  tf2x32(K[6][0], K[6][1], 0u, 0u, kp1[0], kp1[1]);
  tf2x32(K[6][0], K[6][1], 0u, 1u, kp2[0], kp2[1]);
  float r[8];
  for (int i = 0; i < 8; ++i) {
    uint32_t hi = tf_bits32(kp1[0], kp1[1], (uint32_t)i);
    uint32_t lo = tf_bits32(kp2[0], kp2[1], (uint32_t)i);
    uint32_t v = ((hi % span) * mult + (lo % span)) % span;
    r[i] = (float)v;
  }

  // ---- homography: T(end)=start ----
  float w = (float)(S - 1);
  float ex[4] = {r[0], w - r[2], w - r[4], r[6]};
  float ey[4] = {r[1], r[3], w - r[5], w - r[7]};
  float px4[4] = {0.f, w, w, 0.f};
  float py4[4] = {0.f, 0.f, w, w};
  float A[8][8];
  float rhs[8];
  for (int i = 0; i < 4; ++i) {
    A[i][0] = ex[i]; A[i][1] = ey[i]; A[i][2] = 1.f;
    A[i][3] = 0.f;   A[i][4] = 0.f;   A[i][5] = 0.f;
    A[i][6] = -px4[i] * ex[i]; A[i][7] = -px4[i] * ey[i];
    rhs[i] = px4[i];
    A[4 + i][0] = 0.f; A[4 + i][1] = 0.f; A[4 + i][2] = 0.f;
    A[4 + i][3] = ex[i]; A[4 + i][4] = ey[i]; A[4 + i][5] = 1.f;
    A[4 + i][6] = -py4[i] * ex[i]; A[4 + i][7] = -py4[i] * ey[i];
    rhs[4 + i] = py4[i];
  }
  float h[8];
  solve8(A, rhs, h);

  // ---- bbox of batch1 support ----
  float ctr = (float)(S - 1) * 0.5f;
  float a_half = (ctr + 2.0f) * sc;
  float bbh = a_half * (fabsf(cos_t) + fabsf(sin_t)) + 3.0f;
  int blo = (int)floorf(ctr - bbh); if (blo < 0) blo = 0;
  int bhi = (int)ceilf(ctr + bbh);  if (bhi > S - 1) bhi = S - 1;
  int bw = bhi - blo + 1;
  int bwp = (bw + 15) & ~15;

  // ---- host-side conservative interior bbox over (y, x8) groups ----
  int X8 = S / 8;
  int ylo = S, yhi = -1, glo = X8, ghi = -1;
  {
    double H0 = h[0], H1 = h[1], H2 = h[2], H3 = h[3], H4 = h[4], H5 = h[5], H6 = h[6], H7 = h[7];
    double bl = (double)blo - 3.0, bh = (double)bhi + 3.0;
    for (int y = 0; y < S; ++y) {
      double yo = y + 0.5;
      for (int g = 0; g < X8; ++g) {
        double xo0 = g * 8 + 0.5, xo7 = xo0 + 7.0;
        double den0 = H6 * xo0 + H7 * yo + 1.0;
        double den7 = H6 * xo7 + H7 * yo + 1.0;
        bool ext;
        if (den0 > 0.0 && den7 > 0.0) {
          double psx0 = (H0 * xo0 + H1 * yo + H2) / den0 - 0.5;
          double psy0 = (H3 * xo0 + H4 * yo + H5) / den0 - 0.5;
          double psx7 = (H0 * xo7 + H1 * yo + H2) / den7 - 0.5;
          double psy7 = (H3 * xo7 + H4 * yo + H5) / den7 - 0.5;
          double lox = fmin(psx0, psx7), hix = fmax(psx0, psx7);
          double loy = fmin(psy0, psy7), hiy = fmax(psy0, psy7);
          ext = (hix < bl || lox > bh || hiy < bl || loy > bh);
        } else {
          ext = false;
        }
        if (!ext) {
          if (y < ylo) ylo = y;
          if (y > yhi) yhi = y;
          if (g < glo) glo = g;
          if (g > ghi) ghi = g;
        }
      }
    }
  }
  int rows = (yhi >= ylo) ? (yhi - ylo + 1) : 0;
  int gcnt = (ghi >= glo) ? (ghi - glo + 1) : 0;

  // ---- workspace layout (p1 float4/pixel) ----
  size_t psize = (size_t)SS * sizeof(float4);      // 2.77 MB
  float4* p1   = (float4*)d_ws;
  double* part = (double*)((char*)d_ws + psize);
  float*  b1   = (float*)((char*)d_ws + psize + 8192);

  int nbA = (SS + 255) / 256;

  // ---- zero-work partition: Gtot groups -> NZ blocks split A/B/C ----
  int Gtot = N * S * X8;
  int NZ   = (Gtot + 255) / 256;
  int NB1  = (bw * bw * N + 255) / 256;
  int ZB   = (int)((long long)NZ * 42 / 100);
  int ZA   = (NZ - ZB) / 2;
  int ZC   = NZ - ZB - ZA;
  int zA0  = 0;
  int zB0  = ZA * 256;
  int zC0  = (ZA + ZB) * 256;

  // A: resize + zero slice
  k_resize_z<<<nbA + ZA, 256, 0, stream>>>(
      adv, p1, part, bmul, S, inS, SS, nbA,
      zA0, Gtot, N, X8, blo, bhi, (float4*)out,
      h[0], h[1], h[2], h[3], h[4], h[5], h[6], h[7]);

  // B: interleaved hash + zero slice
  int NTOT = NB1 + ZB;
  k_combined<<<NTOT, 256, 0, stream>>>(
      p1, b1, part, nbA, cc, ssat,
      K[3][0], K[3][1], S, SS, blo, bhi, bw, bwp,
      cos_t, sin_t, sc, ctr, N, X8, NB1, NTOT, zB0, Gtot, (float4*)out,
      h[0], h[1], h[2], h[3], h[4], h[5], h[6], h[7]);

  // C: interior + zero slice
  int totalInt = N * rows * gcnt;
  int nbInt = (totalInt + 255) / 256;
  if (totalInt <= 0) nbInt = 0;
  k_out_in_z<<<nbInt + ZC, 256, 0, stream>>>(
      b1, (float4*)out, S, X8, blo, bhi, bw, bwp,
      ylo, rows, glo, gcnt, totalInt, nbInt,
      zC0, Gtot, N,
      h[0], h[1], h[2], h[3], h[4], h[5], h[6], h[7]);
}